// Round 5
// baseline (138.498 us; speedup 1.0000x reference)
//
#include <hip/hip_runtime.h>

typedef unsigned int uint_t;

constexpr int B = 8;
constexpr int N = 1024;
constexpr int NBLOCKS = 256;
constexpr int NTHREADS = 1024;
constexpr int NWAVES = NTHREADS / 64;      // 16
constexpr int BPB = NBLOCKS / B;           // 32 blocks per batch
constexpr int SEG = N / BPB;               // 32 rows per block
constexpr int RPW = SEG / NWAVES;          // 2 rows per wave
constexpr int KPL = N / 64;                // 16 columns per lane
constexpr int MAX_ITER = 100;
constexpr float THRESH = 0.1f;
constexpr float K2 = 14.42695040888963f;         // log2(e)/EPS
constexpr float A2K = 2.0f * K2;
constexpr float NEPSLN2 = -0.06931471805599453f; // -EPS*ln2
constexpr float EPSLOGMU = -0.693146156565634f;  // EPS*log(1/N+1e-8)
constexpr uint_t MAGIC = 0xC0FFEE01u;

// ws word offsets
constexpr int OFF_U      = 0;                    // [B][N]
constexpr int OFF_V      = OFF_U + B * N;        // [B][N]
constexpr int OFF_ERRBLK = OFF_V + B * N;        // [B][32]   written-before-read
constexpr int OFF_ERRBAT = OFF_ERRBLK + 256;     // [100][8]  written-before-read
constexpr int OFF_EMDBLK = OFF_ERRBAT + 800;     // [B][32]   written-before-read
constexpr int OFF_EMDBAT = OFF_EMDBLK + 256;     // [8]       written-before-read
constexpr int OFF_ZERO   = OFF_EMDBAT + 8;       // ---- zeroed region ----
constexpr int OFF_BARFLG = OFF_ZERO;             // [8][32] uint epoch flags
constexpr int OFF_ERRFLG = OFF_BARFLG + 256;     // [8] uint (last published it+1)
constexpr int OFF_EMDFLG = OFF_ERRFLG + 8;       // [8] uint
constexpr int OFF_ZEROEND= OFF_EMDFLG + 8;
constexpr int OFF_INIT   = OFF_ZEROEND;          // [1] uint (MAGIC; poison != MAGIC)

// ---- coherent access helpers: bypass non-coherent L1/L2, no cache-maint ops ----
__device__ __forceinline__ float gload(const float* p) {
  return __hip_atomic_load(p, __ATOMIC_RELAXED, __HIP_MEMORY_SCOPE_AGENT);
}
__device__ __forceinline__ void gstore(float* p, float v) {
  __hip_atomic_store(p, v, __ATOMIC_RELAXED, __HIP_MEMORY_SCOPE_AGENT);
}
__device__ __forceinline__ uint_t lflag(const uint_t* p) {
  return __hip_atomic_load(p, __ATOMIC_RELAXED, __HIP_MEMORY_SCOPE_AGENT);
}
__device__ __forceinline__ void sflag_rel(uint_t* p, uint_t v) {
  __hip_atomic_store(p, v, __ATOMIC_RELEASE, __HIP_MEMORY_SCOPE_AGENT);
}

__device__ __forceinline__ float wsum(float v) {
#pragma unroll
  for (int o = 32; o; o >>= 1) v += __shfl_xor(v, o);
  return v;
}
__device__ __forceinline__ float wmax(float v) {
#pragma unroll
  for (int o = 32; o; o >>= 1) v = fmaxf(v, __shfl_xor(v, o));
  return v;
}

// Deterministic block-wide sum; every thread returns the same value.
__device__ __forceinline__ float block_sum(float v, float* sh) {
  v = wsum(v);
  const int wave = threadIdx.x >> 6;
  const int lane = threadIdx.x & 63;
  if (lane == 0) sh[wave] = v;
  __syncthreads();
  float tot = 0.f;
#pragma unroll
  for (int w = 0; w < NWAVES; ++w) tot += sh[w];
  __syncthreads();
  return tot;
}

// Per-batch barrier: arrival = RELEASE store to a block-private epoch word;
// wave 0 polls all 32 flags with one vector load (RELAXED: coherent, no
// invalidate side effects).
__device__ __forceinline__ void batch_barrier(uint_t* flg, int seg, uint_t epoch,
                                              int lane) {
  __syncthreads();
  if (threadIdx.x == 0) sflag_rel(&flg[seg], epoch);
  if (threadIdx.x < 64) {
    for (;;) {
      uint_t f = (lane < BPB) ? lflag(&flg[lane]) : epoch;
      if (__all(f >= epoch)) break;
      __builtin_amdgcn_s_sleep(1);
    }
  }
  __syncthreads();
}

// One Sinkhorn half-update in base-2 scale (K2 = log2(e)/EPS folded in).
// Computes pnew[RPW] (wave-uniform) WITHOUT storing — caller defers the store
// (speculation support). Cols from SoA LDS (b32 dense = conflict-free),
// rows via wave-uniform broadcasts. err is meaningful on lane 0 only.
template <bool TRACK>
__device__ __forceinline__ float half_compute(
    const float* __restrict__ cx, const float* __restrict__ cy,
    const float* __restrict__ cz, const float* __restrict__ cw,
    const float* __restrict__ rx, const float* __restrict__ ry,
    const float* __restrict__ rz, const float* __restrict__ rw,
    const float* __restrict__ pin, const float* __restrict__ pout_old,
    float (&pnew)[RPW], int i0, int lane, bool pin_zero, bool first_out) {
  float p2[KPL];
#pragma unroll
  for (int k = 0; k < KPL; ++k)
    p2[k] = pin_zero ? 0.f : gload(&pin[lane + (k << 6)]) * K2;

  float a0[RPW], a1[RPW], a2[RPW], X[RPW], m[RPW];
  float vals[RPW][KPL];
#pragma unroll
  for (int rr = 0; rr < RPW; ++rr) {
    a0[rr] = A2K * rx[i0 + rr]; a1[rr] = A2K * ry[i0 + rr];
    a2[rr] = A2K * rz[i0 + rr];
    X[rr] = -rw[i0 + rr];                 // rw = -K2*|r|^2
    m[rr] = -3.4e38f;
  }
#pragma unroll
  for (int k = 0; k < KPL; ++k) {
    const int j = lane + (k << 6);
    float ccx = cx[j], ccy = cy[j], ccz = cz[j];
    float base = cw[j] + p2[k];           // fold pin into the fma chain
#pragma unroll
    for (int rr = 0; rr < RPW; ++rr) {
      float t = fmaf(a0[rr], ccx, fmaf(a1[rr], ccy, fmaf(a2[rr], ccz, base)));
      float val = fminf(t - X[rr], p2[k]);  // = p2 - K2*C
      vals[rr][k] = val;
      m[rr] = fmaxf(m[rr], val);
    }
  }
  float err = 0.f;
#pragma unroll
  for (int rr = 0; rr < RPW; ++rr) {
    float mr = wmax(m[rr]);
    float s = 0.f;
#pragma unroll
    for (int k = 0; k < KPL; ++k)
      s += __builtin_amdgcn_exp2f(vals[rr][k] - mr);
    s = wsum(s);
    float pn = fmaf(NEPSLN2, mr + __builtin_amdgcn_logf(s), EPSLOGMU);
    pnew[rr] = pn;
    if (TRACK && lane == 0) {
      float old = first_out ? 0.f : gload(&pout_old[i0 + rr]);
      err += fabsf(pn - old);
    }
  }
  return err;
}

__device__ __forceinline__ void store_rows(float* p, const float (&pnew)[RPW],
                                           int i0, int lane) {
  if (lane == 0) {
#pragma unroll
    for (int rr = 0; rr < RPW; ++rr) gstore(&p[i0 + rr], pnew[rr]);
  }
}

__global__ void __launch_bounds__(NTHREADS) sinkhorn_kernel(
    const float* __restrict__ xg, const float* __restrict__ yg,
    float* __restrict__ out, float* __restrict__ ws) {
  // SoA LDS: col reads are b32 dense (2-way aliasing = free), row reads are
  // wave-uniform broadcasts. w = -K2*|p|^2.
  __shared__ float s_xx[N], s_xy[N], s_xz[N], s_xw[N];
  __shared__ float s_yx[N], s_yy[N], s_yz[N], s_yw[N];
  __shared__ float sh_red[NWAVES];

  const int bid = blockIdx.x;
  const int tid = threadIdx.x;
  const int b = bid & 7;
  const int seg = bid >> 3;
  const int wave = tid >> 6;
  const int lane = tid & 63;
  const int i0 = seg * SEG + wave * RPW;   // first of this wave's rows

  float* u = ws + OFF_U + b * N;
  float* v = ws + OFF_V + b * N;
  float* err_blk = ws + OFF_ERRBLK + b * 32;
  float* err_bat = ws + OFF_ERRBAT;
  float* emd_blk = ws + OFF_EMDBLK + b * 32;
  float* emd_bat = ws + OFF_EMDBAT;
  uint_t* bar_flg = (uint_t*)(ws + OFF_BARFLG) + b * 32;
  uint_t* err_flg = (uint_t*)(ws + OFF_ERRFLG);
  uint_t* emd_flg = (uint_t*)(ws + OFF_EMDFLG);
  uint_t* init_flag = (uint_t*)(ws + OFF_INIT);

  // Block 0 zeroes the flag region FIRST (ws poisoned 0xAA), then MAGIC.
  if (bid == 0) {
    uint_t* zb = (uint_t*)(ws + OFF_ZERO);
    for (int i = tid; i < OFF_ZEROEND - OFF_ZERO; i += NTHREADS)
      __hip_atomic_store(&zb[i], 0u, __ATOMIC_RELAXED, __HIP_MEMORY_SCOPE_AGENT);
    __syncthreads();
    if (tid == 0) sflag_rel(init_flag, MAGIC);
  }

  // Stage points into LDS (1 point per thread).
  for (int p = tid; p < N; p += NTHREADS) {
    const float* xp = xg + (size_t)(b * N + p) * 3;
    float x0 = xp[0], x1 = xp[1], x2 = xp[2];
    s_xx[p] = x0; s_xy[p] = x1; s_xz[p] = x2;
    s_xw[p] = -K2 * (x0 * x0 + x1 * x1 + x2 * x2);
    const float* yp = yg + (size_t)(b * N + p) * 3;
    float y0 = yp[0], y1 = yp[1], y2 = yp[2];
    s_yx[p] = y0; s_yy[p] = y1; s_yz[p] = y2;
    s_yw[p] = -K2 * (y0 * y0 + y1 * y1 + y2 * y2);
  }
  __syncthreads();

  // ---- u-half(0): u1 from v0=0 (no flags needed yet — init wait is hidden) ----
  float un[RPW];
  float my_err = half_compute<true>(s_yx, s_yy, s_yz, s_yw,
                                    s_xx, s_xy, s_xz, s_xw,
                                    v, u, un, i0, lane,
                                    /*pin_zero=*/true, /*first_out=*/true);
  store_rows(u, un, i0, lane);
  float blk_err = block_sum(my_err, sh_red);
  if (tid == 0) gstore(&err_blk[seg], blk_err);

  // MAGIC wait — overlapped behind u-half(0); only gates flag usage (bar A).
  if (tid == 0 && bid != 0)
    while (lflag(init_flag) != MAGIC) __builtin_amdgcn_s_sleep(2);
  __syncthreads();

  uint_t epoch = 0;
  int it = 0;
  for (;;) {
    ++epoch;
    batch_barrier(bar_flg, seg, epoch, lane);   // bar A: u_{it+1}, err(it) visible

    // ---- v-half(it): v_{it+1} from u_{it+1} ----
    float vn[RPW];
    half_compute<false>(s_xx, s_xy, s_xz, s_xw,
                        s_yx, s_yy, s_yz, s_yw,
                        u, nullptr, vn, i0, lane, false, false);
    store_rows(v, vn, i0, lane);

    // Publish err(it) AFTER v-compute (doesn't delay seg0's bar-B arrival);
    // consumed ~1 half-update later at the decision → poll is pre-satisfied.
    if (seg == 0 && tid < 64) {
      float e = (lane < BPB) ? gload(&err_blk[lane]) : 0.f;
      e = wsum(e);
      if (lane == 0) {
        gstore(&err_bat[it * B + b], e);
        sflag_rel(&err_flg[b], (uint_t)(it + 1));
      }
    }
    ++epoch;
    batch_barrier(bar_flg, seg, epoch, lane);   // bar B: v_{it+1} visible

    if (it == MAX_ITER - 1) break;              // reference caps at 100 steps

    // ---- speculative u-half(it+1): u_{it+2} in regs, store deferred ----
    my_err = half_compute<true>(s_yx, s_yy, s_yz, s_yw,
                                s_xx, s_xy, s_xz, s_xw,
                                v, u, un, i0, lane, false, false);

    // ---- decision(it): flags were published one half-update ago ----
    if (tid < 64) {
      const uint_t want = (uint_t)(it + 1);
      for (;;) {
        uint_t f = (lane < B) ? lflag(&err_flg[lane]) : want;
        if (__all(f >= want)) break;
        __builtin_amdgcn_s_sleep(1);
      }
      float e = (lane < B) ? gload(&err_bat[it * B + lane]) : 0.f;
      e = wsum(e);
      if (lane == 0) sh_red[0] = e;
    }
    __syncthreads();
    float tot = sh_red[0];
    __syncthreads();
    if (tot * (1.f / (B * N)) < THRESH) break;  // converged: keep u_{it+1},v_{it+1}

    // ---- commit speculation (safe: all err(it) readers finished — they set
    // err_flg before we could pass the decision) ----
    store_rows(u, un, i0, lane);
    blk_err = block_sum(my_err, sh_red);
    if (tid == 0) gstore(&err_blk[seg], blk_err);
    ++it;
  }

  // ---- epilogue: emd_b = sum_ij exp((u_i+v_j-C)/EPS)*C  (in K2 scale) ----
  float p2e[KPL];
#pragma unroll
  for (int k = 0; k < KPL; ++k) p2e[k] = gload(&v[lane + (k << 6)]) * K2;
  float acc = 0.f;
#pragma unroll
  for (int rr = 0; rr < RPW; ++rr) {
    const int i = i0 + rr;
    float a0 = A2K * s_xx[i], a1 = A2K * s_xy[i], a2 = A2K * s_xz[i];
    float X = -s_xw[i];
    float u2 = gload(&u[i]) * K2;
#pragma unroll
    for (int k = 0; k < KPL; ++k) {
      const int j = lane + (k << 6);
      float t = fmaf(a0, s_yx[j], fmaf(a1, s_yy[j], fmaf(a2, s_yz[j], s_yw[j])));
      float kc = fmaxf(X - t, 0.f);   // K2*C
      acc = fmaf(__builtin_amdgcn_exp2f(u2 + p2e[k] - kc), kc, acc);
    }
  }
  float blk = block_sum(acc, sh_red);
  const uint_t ef = epoch + 1;        // epoch is block-uniform across the grid
  if (tid == 0) { gstore(&emd_blk[seg], blk); sflag_rel(&bar_flg[seg], ef); }

  // Fused reduction: non-seg0 blocks exit now; seg0 combines its batch;
  // block 0 combines batches. All via flags — no full barrier.
  if (seg == 0 && tid < 64) {
    for (;;) {
      uint_t f = (lane < BPB) ? lflag(&bar_flg[lane]) : ef;
      if (__all(f >= ef)) break;
      __builtin_amdgcn_s_sleep(1);
    }
    float e = (lane < BPB) ? gload(&emd_blk[lane]) : 0.f;
    e = wsum(e);
    if (lane == 0) { gstore(&emd_bat[b], e); sflag_rel(&emd_flg[b], 1u); }
  }
  if (bid == 0 && tid < 64) {
    for (;;) {
      uint_t f = (lane < B) ? lflag(&emd_flg[lane]) : 1u;
      if (__all(f >= 1u)) break;
      __builtin_amdgcn_s_sleep(1);
    }
    float e = (lane < B) ? gload(&emd_bat[lane]) : 0.f;
    e = wsum(e);
    if (lane == 0) out[0] = e * (1.f / (B * K2));
  }
}

extern "C" void kernel_launch(void* const* d_in, const int* in_sizes, int n_in,
                              void* d_out, int out_size, void* d_ws, size_t ws_size,
                              hipStream_t stream) {
  const float* x = (const float*)d_in[0];
  const float* y = (const float*)d_in[1];
  float* out = (float*)d_out;
  float* ws = (float*)d_ws;
  void* args[] = { (void*)&x, (void*)&y, (void*)&out, (void*)&ws };
  // Cooperative launch only for the co-residency guarantee (no cg::grid.sync;
  // all sync is per-batch epoch flags + publish/poll over coherent atomics).
  hipLaunchCooperativeKernel((const void*)sinkhorn_kernel,
                             dim3(NBLOCKS), dim3(NTHREADS), args, 0, stream);
}

// Round 6
// 134.329 us; speedup vs baseline: 1.0310x; 1.0310x over previous
//
#include <hip/hip_runtime.h>

typedef unsigned int uint_t;

constexpr int B = 8;
constexpr int N = 1024;
constexpr int NBLOCKS = 256;
constexpr int NTHREADS = 1024;
constexpr int NWAVES = NTHREADS / 64;      // 16
constexpr int BPB = NBLOCKS / B;           // 32 blocks per batch
constexpr int SEG = N / BPB;               // 32 rows per block
constexpr int RPW = SEG / NWAVES;          // 2 rows per wave
constexpr int KPL = N / 64;                // 16 columns per lane
constexpr int MAX_ITER = 100;
constexpr float THRESH = 0.1f;
constexpr float K2 = 14.42695040888963f;         // log2(e)/EPS
constexpr float A2K = 2.0f * K2;
constexpr float NEPSLN2 = -0.06931471805599453f; // -EPS*ln2
constexpr float EPSLOGMU = -0.693146156565634f;  // EPS*log(1/N+1e-8)
constexpr uint_t MAGIC = 0xC0FFEE01u;

// ws word offsets
constexpr int OFF_U      = 0;                    // [B][N]
constexpr int OFF_V      = OFF_U + B * N;        // [B][N]
constexpr int OFF_ERRBLK = OFF_V + B * N;        // [B][32]   written-before-read
constexpr int OFF_ERRBAT = OFF_ERRBLK + 256;     // [100][8]  written-before-read
constexpr int OFF_EMDBLK = OFF_ERRBAT + 800;     // [B][32]   written-before-read
constexpr int OFF_EMDBAT = OFF_EMDBLK + 256;     // [8]       written-before-read
constexpr int OFF_ZERO   = OFF_EMDBAT + 8;       // ---- zeroed region ----
constexpr int OFF_BARFLG = OFF_ZERO;             // [8][32] uint epoch flags
constexpr int OFF_ERRFLG = OFF_BARFLG + 256;     // [8] uint (last published it+1)
constexpr int OFF_EMDFLG = OFF_ERRFLG + 8;       // [8] uint
constexpr int OFF_ZEROEND= OFF_EMDFLG + 8;
constexpr int OFF_INIT   = OFF_ZEROEND;          // [1] uint (MAGIC; poison != MAGIC)

// ---- coherent access helpers: bypass non-coherent L1/L2, no cache-maint ops ----
__device__ __forceinline__ float gload(const float* p) {
  return __hip_atomic_load(p, __ATOMIC_RELAXED, __HIP_MEMORY_SCOPE_AGENT);
}
__device__ __forceinline__ void gstore(float* p, float v) {
  __hip_atomic_store(p, v, __ATOMIC_RELAXED, __HIP_MEMORY_SCOPE_AGENT);
}
__device__ __forceinline__ uint_t lflag(const uint_t* p) {
  return __hip_atomic_load(p, __ATOMIC_RELAXED, __HIP_MEMORY_SCOPE_AGENT);
}
__device__ __forceinline__ void sflag_rel(uint_t* p, uint_t v) {
  __hip_atomic_store(p, v, __ATOMIC_RELEASE, __HIP_MEMORY_SCOPE_AGENT);
}

__device__ __forceinline__ float wsum(float v) {
#pragma unroll
  for (int o = 32; o; o >>= 1) v += __shfl_xor(v, o);
  return v;
}
__device__ __forceinline__ float wmax(float v) {
#pragma unroll
  for (int o = 32; o; o >>= 1) v = fmaxf(v, __shfl_xor(v, o));
  return v;
}

// Deterministic block-wide sum; every thread returns the same value.
__device__ __forceinline__ float block_sum(float v, float* sh) {
  v = wsum(v);
  const int wave = threadIdx.x >> 6;
  const int lane = threadIdx.x & 63;
  if (lane == 0) sh[wave] = v;
  __syncthreads();
  float tot = 0.f;
#pragma unroll
  for (int w = 0; w < NWAVES; ++w) tot += sh[w];
  __syncthreads();
  return tot;
}

// Per-batch barrier: arrival = RELEASE store to a block-private epoch word;
// wave 0 polls all 32 flags with one vector load (RELAXED: coherent, no
// invalidate side effects).
__device__ __forceinline__ void batch_barrier(uint_t* flg, int seg, uint_t epoch,
                                              int lane) {
  __syncthreads();
  if (threadIdx.x == 0) sflag_rel(&flg[seg], epoch);
  if (threadIdx.x < 64) {
    for (;;) {
      uint_t f = (lane < BPB) ? lflag(&flg[lane]) : epoch;
      if (__all(f >= epoch)) break;
      __builtin_amdgcn_s_sleep(1);
    }
  }
  __syncthreads();
}

// One Sinkhorn half-update in base-2 scale (K2 = log2(e)/EPS folded in).
// Computes pnew[RPW] (wave-uniform) WITHOUT storing — caller defers the store
// (speculation support). Cols from SoA LDS (b32 dense = conflict-free),
// rows via wave-uniform broadcasts. err is meaningful on lane 0 only.
template <bool TRACK>
__device__ __forceinline__ float half_compute(
    const float* __restrict__ cx, const float* __restrict__ cy,
    const float* __restrict__ cz, const float* __restrict__ cw,
    const float* __restrict__ rx, const float* __restrict__ ry,
    const float* __restrict__ rz, const float* __restrict__ rw,
    const float* __restrict__ pin, const float* __restrict__ pout_old,
    float (&pnew)[RPW], int i0, int lane, bool pin_zero, bool first_out) {
  float p2[KPL];
#pragma unroll
  for (int k = 0; k < KPL; ++k)
    p2[k] = pin_zero ? 0.f : gload(&pin[lane + (k << 6)]) * K2;

  float a0[RPW], a1[RPW], a2[RPW], X[RPW], m[RPW];
  float vals[RPW][KPL];
#pragma unroll
  for (int rr = 0; rr < RPW; ++rr) {
    a0[rr] = A2K * rx[i0 + rr]; a1[rr] = A2K * ry[i0 + rr];
    a2[rr] = A2K * rz[i0 + rr];
    X[rr] = -rw[i0 + rr];                 // rw = -K2*|r|^2
    m[rr] = -3.4e38f;
  }
#pragma unroll
  for (int k = 0; k < KPL; ++k) {
    const int j = lane + (k << 6);
    float ccx = cx[j], ccy = cy[j], ccz = cz[j];
    float base = cw[j] + p2[k];           // fold pin into the fma chain
#pragma unroll
    for (int rr = 0; rr < RPW; ++rr) {
      float t = fmaf(a0[rr], ccx, fmaf(a1[rr], ccy, fmaf(a2[rr], ccz, base)));
      float val = fminf(t - X[rr], p2[k]);  // = p2 - K2*C
      vals[rr][k] = val;
      m[rr] = fmaxf(m[rr], val);
    }
  }
  float err = 0.f;
#pragma unroll
  for (int rr = 0; rr < RPW; ++rr) {
    float mr = wmax(m[rr]);
    float s = 0.f;
#pragma unroll
    for (int k = 0; k < KPL; ++k)
      s += __builtin_amdgcn_exp2f(vals[rr][k] - mr);
    s = wsum(s);
    float pn = fmaf(NEPSLN2, mr + __builtin_amdgcn_logf(s), EPSLOGMU);
    pnew[rr] = pn;
    if (TRACK && lane == 0) {
      float old = first_out ? 0.f : gload(&pout_old[i0 + rr]);
      err += fabsf(pn - old);
    }
  }
  return err;
}

__device__ __forceinline__ void store_rows(float* p, const float (&pnew)[RPW],
                                           int i0, int lane) {
  if (lane == 0) {
#pragma unroll
    for (int rr = 0; rr < RPW; ++rr) gstore(&p[i0 + rr], pnew[rr]);
  }
}

// __launch_bounds__(1024, 4): 4 waves/SIMD = 16 waves/CU = exactly our
// 1 block/CU (LDS 33 KB caps us there anyway). Without this the compiler
// budgets 64 VGPRs (2 blocks/CU) and spills vals[]+p2[] to scratch —
// R5 measured 47 MB/dispatch of HBM spill traffic (FETCH 12.6 MB,
// WRITE 33.9 MB, VGPR_Count 64). This hint is the whole R6 change.
__global__ void __launch_bounds__(NTHREADS, 4) sinkhorn_kernel(
    const float* __restrict__ xg, const float* __restrict__ yg,
    float* __restrict__ out, float* __restrict__ ws) {
  // SoA LDS: col reads are b32 dense (2-way aliasing = free), row reads are
  // wave-uniform broadcasts. w = -K2*|p|^2.
  __shared__ float s_xx[N], s_xy[N], s_xz[N], s_xw[N];
  __shared__ float s_yx[N], s_yy[N], s_yz[N], s_yw[N];
  __shared__ float sh_red[NWAVES];

  const int bid = blockIdx.x;
  const int tid = threadIdx.x;
  const int b = bid & 7;
  const int seg = bid >> 3;
  const int wave = tid >> 6;
  const int lane = tid & 63;
  const int i0 = seg * SEG + wave * RPW;   // first of this wave's rows

  float* u = ws + OFF_U + b * N;
  float* v = ws + OFF_V + b * N;
  float* err_blk = ws + OFF_ERRBLK + b * 32;
  float* err_bat = ws + OFF_ERRBAT;
  float* emd_blk = ws + OFF_EMDBLK + b * 32;
  float* emd_bat = ws + OFF_EMDBAT;
  uint_t* bar_flg = (uint_t*)(ws + OFF_BARFLG) + b * 32;
  uint_t* err_flg = (uint_t*)(ws + OFF_ERRFLG);
  uint_t* emd_flg = (uint_t*)(ws + OFF_EMDFLG);
  uint_t* init_flag = (uint_t*)(ws + OFF_INIT);

  // Block 0 zeroes the flag region FIRST (ws poisoned 0xAA), then MAGIC.
  if (bid == 0) {
    uint_t* zb = (uint_t*)(ws + OFF_ZERO);
    for (int i = tid; i < OFF_ZEROEND - OFF_ZERO; i += NTHREADS)
      __hip_atomic_store(&zb[i], 0u, __ATOMIC_RELAXED, __HIP_MEMORY_SCOPE_AGENT);
    __syncthreads();
    if (tid == 0) sflag_rel(init_flag, MAGIC);
  }

  // Stage points into LDS (1 point per thread).
  for (int p = tid; p < N; p += NTHREADS) {
    const float* xp = xg + (size_t)(b * N + p) * 3;
    float x0 = xp[0], x1 = xp[1], x2 = xp[2];
    s_xx[p] = x0; s_xy[p] = x1; s_xz[p] = x2;
    s_xw[p] = -K2 * (x0 * x0 + x1 * x1 + x2 * x2);
    const float* yp = yg + (size_t)(b * N + p) * 3;
    float y0 = yp[0], y1 = yp[1], y2 = yp[2];
    s_yx[p] = y0; s_yy[p] = y1; s_yz[p] = y2;
    s_yw[p] = -K2 * (y0 * y0 + y1 * y1 + y2 * y2);
  }
  __syncthreads();

  // ---- u-half(0): u1 from v0=0 (no flags needed yet — init wait is hidden) ----
  float un[RPW];
  float my_err = half_compute<true>(s_yx, s_yy, s_yz, s_yw,
                                    s_xx, s_xy, s_xz, s_xw,
                                    v, u, un, i0, lane,
                                    /*pin_zero=*/true, /*first_out=*/true);
  store_rows(u, un, i0, lane);
  float blk_err = block_sum(my_err, sh_red);
  if (tid == 0) gstore(&err_blk[seg], blk_err);

  // MAGIC wait — overlapped behind u-half(0); only gates flag usage (bar A).
  if (tid == 0 && bid != 0)
    while (lflag(init_flag) != MAGIC) __builtin_amdgcn_s_sleep(2);
  __syncthreads();

  uint_t epoch = 0;
  int it = 0;
  for (;;) {
    ++epoch;
    batch_barrier(bar_flg, seg, epoch, lane);   // bar A: u_{it+1}, err(it) visible

    // ---- v-half(it): v_{it+1} from u_{it+1} ----
    float vn[RPW];
    half_compute<false>(s_xx, s_xy, s_xz, s_xw,
                        s_yx, s_yy, s_yz, s_yw,
                        u, nullptr, vn, i0, lane, false, false);
    store_rows(v, vn, i0, lane);

    // Publish err(it) AFTER v-compute (doesn't delay seg0's bar-B arrival);
    // consumed ~1 half-update later at the decision → poll is pre-satisfied.
    if (seg == 0 && tid < 64) {
      float e = (lane < BPB) ? gload(&err_blk[lane]) : 0.f;
      e = wsum(e);
      if (lane == 0) {
        gstore(&err_bat[it * B + b], e);
        sflag_rel(&err_flg[b], (uint_t)(it + 1));
      }
    }
    ++epoch;
    batch_barrier(bar_flg, seg, epoch, lane);   // bar B: v_{it+1} visible

    if (it == MAX_ITER - 1) break;              // reference caps at 100 steps

    // ---- speculative u-half(it+1): u_{it+2} in regs, store deferred ----
    my_err = half_compute<true>(s_yx, s_yy, s_yz, s_yw,
                                s_xx, s_xy, s_xz, s_xw,
                                v, u, un, i0, lane, false, false);

    // ---- decision(it): flags were published one half-update ago ----
    if (tid < 64) {
      const uint_t want = (uint_t)(it + 1);
      for (;;) {
        uint_t f = (lane < B) ? lflag(&err_flg[lane]) : want;
        if (__all(f >= want)) break;
        __builtin_amdgcn_s_sleep(1);
      }
      float e = (lane < B) ? gload(&err_bat[it * B + lane]) : 0.f;
      e = wsum(e);
      if (lane == 0) sh_red[0] = e;
    }
    __syncthreads();
    float tot = sh_red[0];
    __syncthreads();
    if (tot * (1.f / (B * N)) < THRESH) break;  // converged: keep u_{it+1},v_{it+1}

    // ---- commit speculation (safe: all err(it) readers finished — they set
    // err_flg before we could pass the decision) ----
    store_rows(u, un, i0, lane);
    blk_err = block_sum(my_err, sh_red);
    if (tid == 0) gstore(&err_blk[seg], blk_err);
    ++it;
  }

  // ---- epilogue: emd_b = sum_ij exp((u_i+v_j-C)/EPS)*C  (in K2 scale) ----
  float p2e[KPL];
#pragma unroll
  for (int k = 0; k < KPL; ++k) p2e[k] = gload(&v[lane + (k << 6)]) * K2;
  float acc = 0.f;
#pragma unroll
  for (int rr = 0; rr < RPW; ++rr) {
    const int i = i0 + rr;
    float a0 = A2K * s_xx[i], a1 = A2K * s_xy[i], a2 = A2K * s_xz[i];
    float X = -s_xw[i];
    float u2 = gload(&u[i]) * K2;
#pragma unroll
    for (int k = 0; k < KPL; ++k) {
      const int j = lane + (k << 6);
      float t = fmaf(a0, s_yx[j], fmaf(a1, s_yy[j], fmaf(a2, s_yz[j], s_yw[j])));
      float kc = fmaxf(X - t, 0.f);   // K2*C
      acc = fmaf(__builtin_amdgcn_exp2f(u2 + p2e[k] - kc), kc, acc);
    }
  }
  float blk = block_sum(acc, sh_red);
  const uint_t ef = epoch + 1;        // epoch is block-uniform across the grid
  if (tid == 0) { gstore(&emd_blk[seg], blk); sflag_rel(&bar_flg[seg], ef); }

  // Fused reduction: non-seg0 blocks exit now; seg0 combines its batch;
  // block 0 combines batches. All via flags — no full barrier.
  if (seg == 0 && tid < 64) {
    for (;;) {
      uint_t f = (lane < BPB) ? lflag(&bar_flg[lane]) : ef;
      if (__all(f >= ef)) break;
      __builtin_amdgcn_s_sleep(1);
    }
    float e = (lane < BPB) ? gload(&emd_blk[lane]) : 0.f;
    e = wsum(e);
    if (lane == 0) { gstore(&emd_bat[b], e); sflag_rel(&emd_flg[b], 1u); }
  }
  if (bid == 0 && tid < 64) {
    for (;;) {
      uint_t f = (lane < B) ? lflag(&emd_flg[lane]) : 1u;
      if (__all(f >= 1u)) break;
      __builtin_amdgcn_s_sleep(1);
    }
    float e = (lane < B) ? gload(&emd_bat[lane]) : 0.f;
    e = wsum(e);
    if (lane == 0) out[0] = e * (1.f / (B * K2));
  }
}

extern "C" void kernel_launch(void* const* d_in, const int* in_sizes, int n_in,
                              void* d_out, int out_size, void* d_ws, size_t ws_size,
                              hipStream_t stream) {
  const float* x = (const float*)d_in[0];
  const float* y = (const float*)d_in[1];
  float* out = (float*)d_out;
  float* ws = (float*)d_ws;
  void* args[] = { (void*)&x, (void*)&y, (void*)&out, (void*)&ws };
  // Cooperative launch only for the co-residency guarantee (no cg::grid.sync;
  // all sync is per-batch epoch flags + publish/poll over coherent atomics).
  hipLaunchCooperativeKernel((const void*)sinkhorn_kernel,
                             dim3(NBLOCKS), dim3(NTHREADS), args, 0, stream);
}

// Round 7
// 124.508 us; speedup vs baseline: 1.1124x; 1.0789x over previous
//
#include <hip/hip_runtime.h>

typedef unsigned int uint_t;

constexpr int B = 8;
constexpr int N = 1024;
constexpr int NBLOCKS = 256;
constexpr int NTHREADS = 512;              // R4-proven regime: VGPR 96, no spill
constexpr int NWAVES = NTHREADS / 64;      // 8
constexpr int BPB = NBLOCKS / B;           // 32 blocks per batch
constexpr int SEG = N / BPB;               // 32 rows per block
constexpr int RPW = SEG / NWAVES;          // 4 rows per wave
constexpr int KPL = N / 64;                // 16 columns per lane
constexpr int MAX_ITER = 100;
constexpr float THRESH = 0.1f;
constexpr float K2 = 14.42695040888963f;         // log2(e)/EPS
constexpr float A2K = 2.0f * K2;
constexpr float NEPSLN2 = -0.06931471805599453f; // -EPS*ln2
constexpr float EPSLOGMU = -0.693146156565634f;  // EPS*log(1/N+1e-8)
constexpr uint_t MAGIC = 0xC0FFEE01u;

// ws word offsets
constexpr int OFF_U      = 0;                    // [B][N]
constexpr int OFF_V      = OFF_U + B * N;        // [B][N]
constexpr int OFF_ERRBLK = OFF_V + B * N;        // [B][32]   written-before-read
constexpr int OFF_ERRBAT = OFF_ERRBLK + 256;     // [100][8]  written-before-read
constexpr int OFF_EMDBLK = OFF_ERRBAT + 800;     // [B][32]   written-before-read
constexpr int OFF_EMDBAT = OFF_EMDBLK + 256;     // [8]       written-before-read
constexpr int OFF_ZERO   = OFF_EMDBAT + 8;       // ---- zeroed region ----
constexpr int OFF_BARFLG = OFF_ZERO;             // [8][32] uint epoch flags
constexpr int OFF_ERRFLG = OFF_BARFLG + 256;     // [8] uint (last published it+1)
constexpr int OFF_EMDFLG = OFF_ERRFLG + 8;       // [8] uint
constexpr int OFF_ZEROEND= OFF_EMDFLG + 8;
constexpr int OFF_INIT   = OFF_ZEROEND;          // [1] uint (MAGIC; poison != MAGIC)

// ---- coherent access helpers: bypass non-coherent L1/L2, no cache-maint ops ----
__device__ __forceinline__ float gload(const float* p) {
  return __hip_atomic_load(p, __ATOMIC_RELAXED, __HIP_MEMORY_SCOPE_AGENT);
}
__device__ __forceinline__ void gstore(float* p, float v) {
  __hip_atomic_store(p, v, __ATOMIC_RELAXED, __HIP_MEMORY_SCOPE_AGENT);
}
__device__ __forceinline__ uint_t lflag(const uint_t* p) {
  return __hip_atomic_load(p, __ATOMIC_RELAXED, __HIP_MEMORY_SCOPE_AGENT);
}
__device__ __forceinline__ void sflag_rel(uint_t* p, uint_t v) {
  __hip_atomic_store(p, v, __ATOMIC_RELEASE, __HIP_MEMORY_SCOPE_AGENT);
}

__device__ __forceinline__ float wsum(float v) {
#pragma unroll
  for (int o = 32; o; o >>= 1) v += __shfl_xor(v, o);
  return v;
}
__device__ __forceinline__ float wmax(float v) {
#pragma unroll
  for (int o = 32; o; o >>= 1) v = fmaxf(v, __shfl_xor(v, o));
  return v;
}

// Deterministic block-wide sum; every thread returns the same value.
__device__ __forceinline__ float block_sum(float v, float* sh) {
  v = wsum(v);
  const int wave = threadIdx.x >> 6;
  const int lane = threadIdx.x & 63;
  if (lane == 0) sh[wave] = v;
  __syncthreads();
  float tot = 0.f;
#pragma unroll
  for (int w = 0; w < NWAVES; ++w) tot += sh[w];
  __syncthreads();
  return tot;
}

// Per-batch barrier: arrival = RELEASE store to a block-private epoch word;
// wave 0 polls all 32 flags with one vector load (RELAXED: coherent, no
// invalidate side effects).
__device__ __forceinline__ void batch_barrier(uint_t* flg, int seg, uint_t epoch,
                                              int lane) {
  __syncthreads();
  if (threadIdx.x == 0) sflag_rel(&flg[seg], epoch);
  if (threadIdx.x < 64) {
    for (;;) {
      uint_t f = (lane < BPB) ? lflag(&flg[lane]) : epoch;
      if (__all(f >= epoch)) break;
      __builtin_amdgcn_s_sleep(1);
    }
  }
  __syncthreads();
}

// One Sinkhorn half-update in base-2 scale (K2 = log2(e)/EPS folded in).
// Computes pnew[RPW] (wave-uniform) WITHOUT storing — caller defers the store
// (speculation support). Cols/rows from AoS float4 LDS: col b128 reads are
// 2-way bank-aliased (free, m136; R4 measured 0 conflicts), rows are
// wave-uniform broadcasts. err is meaningful on lane 0 only.
template <bool TRACK>
__device__ __forceinline__ float half_compute(
    const float4* __restrict__ c, const float4* __restrict__ r,
    const float* __restrict__ pin, const float* __restrict__ pout_old,
    float (&pnew)[RPW], int i0, int lane, bool pin_zero, bool first_out) {
  float p2[KPL];
#pragma unroll
  for (int k = 0; k < KPL; ++k)
    p2[k] = pin_zero ? 0.f : gload(&pin[lane + (k << 6)]) * K2;

  float a0[RPW], a1[RPW], a2[RPW], X[RPW], m[RPW];
  float vals[RPW][KPL];
#pragma unroll
  for (int rr = 0; rr < RPW; ++rr) {
    float4 r4 = r[i0 + rr];               // wave-uniform broadcast
    a0[rr] = A2K * r4.x; a1[rr] = A2K * r4.y; a2[rr] = A2K * r4.z;
    X[rr] = -r4.w;                        // r4.w = -K2*|r|^2
    m[rr] = -3.4e38f;
  }
#pragma unroll
  for (int k = 0; k < KPL; ++k) {
    float4 c4 = c[lane + (k << 6)];       // ds_read_b128, conflict-free
    float base = c4.w + p2[k];            // fold pin into the fma chain
#pragma unroll
    for (int rr = 0; rr < RPW; ++rr) {
      float t = fmaf(a0[rr], c4.x, fmaf(a1[rr], c4.y, fmaf(a2[rr], c4.z, base)));
      float val = fminf(t - X[rr], p2[k]);  // = p2 - K2*max(C,0)
      vals[rr][k] = val;
      m[rr] = fmaxf(m[rr], val);
    }
  }
  float err = 0.f;
#pragma unroll
  for (int rr = 0; rr < RPW; ++rr) {
    float mr = wmax(m[rr]);
    float s = 0.f;
#pragma unroll
    for (int k = 0; k < KPL; ++k)
      s += __builtin_amdgcn_exp2f(vals[rr][k] - mr);
    s = wsum(s);
    float pn = fmaf(NEPSLN2, mr + __builtin_amdgcn_logf(s), EPSLOGMU);
    pnew[rr] = pn;
    if (TRACK && lane == 0) {
      float old = first_out ? 0.f : gload(&pout_old[i0 + rr]);
      err += fabsf(pn - old);
    }
  }
  return err;
}

__device__ __forceinline__ void store_rows(float* p, const float (&pnew)[RPW],
                                           int i0, int lane) {
  if (lane == 0) {
#pragma unroll
    for (int rr = 0; rr < RPW; ++rr) gstore(&p[i0 + rr], pnew[rr]);
  }
}

// launch_bounds(512,2): R4-proven — VGPR budget 256, compiled at 96, zero
// spill. (1024-thread variants: compiler pins 64 VGPRs and spills 33 MB/
// dispatch to scratch — R5/R6 measured; the 2nd launch_bounds arg cannot
// raise the budget there.)
__global__ void __launch_bounds__(NTHREADS, 2) sinkhorn_kernel(
    const float* __restrict__ xg, const float* __restrict__ yg,
    float* __restrict__ out, float* __restrict__ ws) {
  __shared__ float4 s_x4[N];   // (x0,x1,x2, -K2*|x|^2)
  __shared__ float4 s_y4[N];
  __shared__ float sh_red[NWAVES];

  const int bid = blockIdx.x;
  const int tid = threadIdx.x;
  const int b = bid & 7;
  const int seg = bid >> 3;
  const int wave = tid >> 6;
  const int lane = tid & 63;
  const int i0 = seg * SEG + wave * RPW;   // first of this wave's rows

  float* u = ws + OFF_U + b * N;
  float* v = ws + OFF_V + b * N;
  float* err_blk = ws + OFF_ERRBLK + b * 32;
  float* err_bat = ws + OFF_ERRBAT;
  float* emd_blk = ws + OFF_EMDBLK + b * 32;
  float* emd_bat = ws + OFF_EMDBAT;
  uint_t* bar_flg = (uint_t*)(ws + OFF_BARFLG) + b * 32;
  uint_t* err_flg = (uint_t*)(ws + OFF_ERRFLG);
  uint_t* emd_flg = (uint_t*)(ws + OFF_EMDFLG);
  uint_t* init_flag = (uint_t*)(ws + OFF_INIT);

  // Block 0 zeroes the flag region FIRST (ws poisoned 0xAA), then MAGIC.
  if (bid == 0) {
    uint_t* zb = (uint_t*)(ws + OFF_ZERO);
    for (int i = tid; i < OFF_ZEROEND - OFF_ZERO; i += NTHREADS)
      __hip_atomic_store(&zb[i], 0u, __ATOMIC_RELAXED, __HIP_MEMORY_SCOPE_AGENT);
    __syncthreads();
    if (tid == 0) sflag_rel(init_flag, MAGIC);
  }

  // Stage points into LDS.
  for (int p = tid; p < N; p += NTHREADS) {
    const float* xp = xg + (size_t)(b * N + p) * 3;
    float x0 = xp[0], x1 = xp[1], x2 = xp[2];
    s_x4[p] = make_float4(x0, x1, x2, -K2 * (x0 * x0 + x1 * x1 + x2 * x2));
    const float* yp = yg + (size_t)(b * N + p) * 3;
    float y0 = yp[0], y1 = yp[1], y2 = yp[2];
    s_y4[p] = make_float4(y0, y1, y2, -K2 * (y0 * y0 + y1 * y1 + y2 * y2));
  }
  __syncthreads();

  // ---- u-half(0): u1 from v0=0 (no flags needed yet — init wait is hidden) ----
  float un[RPW];
  float my_err = half_compute<true>(s_y4, s_x4, v, u, un, i0, lane,
                                    /*pin_zero=*/true, /*first_out=*/true);
  store_rows(u, un, i0, lane);
  float blk_err = block_sum(my_err, sh_red);
  if (tid == 0) gstore(&err_blk[seg], blk_err);

  // MAGIC wait — overlapped behind u-half(0); only gates flag usage (bar A).
  if (tid == 0 && bid != 0)
    while (lflag(init_flag) != MAGIC) __builtin_amdgcn_s_sleep(2);
  __syncthreads();

  uint_t epoch = 0;
  int it = 0;
  for (;;) {
    ++epoch;
    batch_barrier(bar_flg, seg, epoch, lane);   // bar A: u_{it+1}, err(it) visible

    // ---- v-half(it): v_{it+1} from u_{it+1} ----
    float vn[RPW];
    half_compute<false>(s_x4, s_y4, u, nullptr, vn, i0, lane, false, false);
    store_rows(v, vn, i0, lane);

    // Publish err(it) AFTER v-compute (doesn't delay seg0's bar-B arrival);
    // consumed ~1 half-update later at the decision → poll is pre-satisfied.
    if (seg == 0 && tid < 64) {
      float e = (lane < BPB) ? gload(&err_blk[lane]) : 0.f;
      e = wsum(e);
      if (lane == 0) {
        gstore(&err_bat[it * B + b], e);
        sflag_rel(&err_flg[b], (uint_t)(it + 1));
      }
    }
    ++epoch;
    batch_barrier(bar_flg, seg, epoch, lane);   // bar B: v_{it+1} visible

    if (it == MAX_ITER - 1) break;              // reference caps at 100 steps

    // ---- speculative u-half(it+1): u_{it+2} in regs, store deferred ----
    my_err = half_compute<true>(s_y4, s_x4, v, u, un, i0, lane, false, false);

    // ---- decision(it): flags were published one half-update ago ----
    if (tid < 64) {
      const uint_t want = (uint_t)(it + 1);
      for (;;) {
        uint_t f = (lane < B) ? lflag(&err_flg[lane]) : want;
        if (__all(f >= want)) break;
        __builtin_amdgcn_s_sleep(1);
      }
      float e = (lane < B) ? gload(&err_bat[it * B + lane]) : 0.f;
      e = wsum(e);
      if (lane == 0) sh_red[0] = e;
    }
    __syncthreads();
    float tot = sh_red[0];
    __syncthreads();
    if (tot * (1.f / (B * N)) < THRESH) break;  // converged: keep u_{it+1},v_{it+1}

    // ---- commit speculation (safe: all err(it) readers finished — they set
    // err_flg before we could pass the decision) ----
    store_rows(u, un, i0, lane);
    blk_err = block_sum(my_err, sh_red);
    if (tid == 0) gstore(&err_blk[seg], blk_err);
    ++it;
  }

  // ---- epilogue: emd_b = sum_ij exp((u_i+v_j-C)/EPS)*C  (in K2 scale) ----
  float p2e[KPL];
#pragma unroll
  for (int k = 0; k < KPL; ++k) p2e[k] = gload(&v[lane + (k << 6)]) * K2;
  float acc = 0.f;
#pragma unroll
  for (int rr = 0; rr < RPW; ++rr) {
    const int i = i0 + rr;
    float4 r4 = s_x4[i];
    float a0 = A2K * r4.x, a1 = A2K * r4.y, a2 = A2K * r4.z;
    float X = -r4.w;
    float u2 = gload(&u[i]) * K2;
#pragma unroll
    for (int k = 0; k < KPL; ++k) {
      float4 c4 = s_y4[lane + (k << 6)];
      float t = fmaf(a0, c4.x, fmaf(a1, c4.y, fmaf(a2, c4.z, c4.w)));
      float kc = fmaxf(X - t, 0.f);   // K2*C
      acc = fmaf(__builtin_amdgcn_exp2f(u2 + p2e[k] - kc), kc, acc);
    }
  }
  float blk = block_sum(acc, sh_red);
  const uint_t ef = epoch + 1;        // epoch is block-uniform across the grid
  if (tid == 0) { gstore(&emd_blk[seg], blk); sflag_rel(&bar_flg[seg], ef); }

  // Fused reduction: non-seg0 blocks exit now; seg0 combines its batch;
  // block 0 combines batches. All via flags — no full barrier.
  if (seg == 0 && tid < 64) {
    for (;;) {
      uint_t f = (lane < BPB) ? lflag(&bar_flg[lane]) : ef;
      if (__all(f >= ef)) break;
      __builtin_amdgcn_s_sleep(1);
    }
    float e = (lane < BPB) ? gload(&emd_blk[lane]) : 0.f;
    e = wsum(e);
    if (lane == 0) { gstore(&emd_bat[b], e); sflag_rel(&emd_flg[b], 1u); }
  }
  if (bid == 0 && tid < 64) {
    for (;;) {
      uint_t f = (lane < B) ? lflag(&emd_flg[lane]) : 1u;
      if (__all(f >= 1u)) break;
      __builtin_amdgcn_s_sleep(1);
    }
    float e = (lane < B) ? gload(&emd_bat[lane]) : 0.f;
    e = wsum(e);
    if (lane == 0) out[0] = e * (1.f / (B * K2));
  }
}

extern "C" void kernel_launch(void* const* d_in, const int* in_sizes, int n_in,
                              void* d_out, int out_size, void* d_ws, size_t ws_size,
                              hipStream_t stream) {
  const float* x = (const float*)d_in[0];
  const float* y = (const float*)d_in[1];
  float* out = (float*)d_out;
  float* ws = (float*)d_ws;
  void* args[] = { (void*)&x, (void*)&y, (void*)&out, (void*)&ws };
  // Cooperative launch only for the co-residency guarantee (no cg::grid.sync;
  // all sync is per-batch epoch flags + publish/poll over coherent atomics).
  hipLaunchCooperativeKernel((const void*)sinkhorn_kernel,
                             dim3(NBLOCKS), dim3(NTHREADS), args, 0, stream);
}

// Round 8
// 110.324 us; speedup vs baseline: 1.2554x; 1.1286x over previous
//
#include <hip/hip_runtime.h>

typedef unsigned int uint_t;
typedef unsigned long long u64_t;

constexpr int B = 8;
constexpr int N = 1024;
constexpr int NBLOCKS = 256;
constexpr int NTHREADS = 512;              // proven regime: ~84-100 VGPR, no spill
constexpr int NWAVES = NTHREADS / 64;      // 8
constexpr int BPB = NBLOCKS / B;           // 32 blocks per batch
constexpr int SEG = N / BPB;               // 32 rows per block
constexpr int RPW = SEG / NWAVES;          // 4 rows per wave
constexpr int KPL = N / 64;                // 16 columns per lane
constexpr int MAX_ITER = 100;
constexpr float THRESH = 0.1f;
constexpr float K2 = 14.42695040888963f;         // log2(e)/EPS
constexpr float A2K = 2.0f * K2;
constexpr float NEPSLN2 = -0.06931471805599453f; // -EPS*ln2
constexpr float EPSLOGMU = -0.693146156565634f;  // EPS*log(1/N+1e-8)
constexpr uint_t MAGIC = 0xC0FFEE01u;

// ws word offsets (all flag offsets even -> 8B aligned)
constexpr int OFF_U    = 0;                 // [B][N] floats
constexpr int OFF_V    = OFF_U + B * N;     // [B][N]
constexpr int OFF_ZERO = OFF_V + B * N;     // ---- zeroed region (u64 flags) ----
constexpr int OFF_FLGA = OFF_ZERO;          // [8][32] u64: (epoch<<32)|err_bits
constexpr int OFF_FLGB = OFF_FLGA + 512;    // [8][32] u64: (epoch<<32)|payload
constexpr int OFF_ERRB = OFF_FLGB + 512;    // [4][8] u64 ring: (it+1<<32)|batch_err
constexpr int OFF_EMD  = OFF_ERRB + 64;     // [8] u64: (1<<32)|batch_emd
constexpr int OFF_ZEROEND = OFF_EMD + 16;   // 1104 words = 552 qwords
constexpr int OFF_INIT = OFF_ZEROEND;       // [1] uint (MAGIC; poison != MAGIC)

// ---- coherent (sc1) access helpers: bypass non-coherent L1/L2 ----
__device__ __forceinline__ float gload(const float* p) {
  return __hip_atomic_load(p, __ATOMIC_RELAXED, __HIP_MEMORY_SCOPE_AGENT);
}
__device__ __forceinline__ void gstore(float* p, float v) {
  __hip_atomic_store(p, v, __ATOMIC_RELAXED, __HIP_MEMORY_SCOPE_AGENT);
}
__device__ __forceinline__ uint_t l32(const uint_t* p) {
  return __hip_atomic_load(p, __ATOMIC_RELAXED, __HIP_MEMORY_SCOPE_AGENT);
}
__device__ __forceinline__ void s32(uint_t* p, uint_t v) {
  __hip_atomic_store(p, v, __ATOMIC_RELAXED, __HIP_MEMORY_SCOPE_AGENT);
}
__device__ __forceinline__ u64_t l64(const u64_t* p) {
  return __hip_atomic_load(p, __ATOMIC_RELAXED, __HIP_MEMORY_SCOPE_AGENT);
}
__device__ __forceinline__ void s64(u64_t* p, u64_t v) {
  __hip_atomic_store(p, v, __ATOMIC_RELAXED, __HIP_MEMORY_SCOPE_AGENT);
}
// Per-wave drain: own vm/lgkm counters to 0 — our stores are acked at the
// coherence point. This replaces RELEASE-store lowering (which may emit
// extra cache-maintenance) with exactly the required semantics.
__device__ __forceinline__ void drain() { __builtin_amdgcn_s_waitcnt(0); }

__device__ __forceinline__ u64_t pk64(uint_t tag, float v) {
  return ((u64_t)tag << 32) | (u64_t)__float_as_uint(v);
}

__device__ __forceinline__ float wsum(float v) {
#pragma unroll
  for (int o = 32; o; o >>= 1) v += __shfl_xor(v, o);
  return v;
}
__device__ __forceinline__ float wmax(float v) {
#pragma unroll
  for (int o = 32; o; o >>= 1) v = fmaxf(v, __shfl_xor(v, o));
  return v;
}

// Deterministic block-wide sum; every thread returns the same value.
__device__ __forceinline__ float block_sum(float v, float* sh) {
  v = wsum(v);
  const int wave = threadIdx.x >> 6;
  const int lane = threadIdx.x & 63;
  if (lane == 0) sh[wave] = v;
  __syncthreads();
  float tot = 0.f;
#pragma unroll
  for (int w = 0; w < NWAVES; ++w) tot += sh[w];
  __syncthreads();
  return tot;
}

// One Sinkhorn half-update in base-2 scale (K2 = log2(e)/EPS folded in).
// SoA LDS: col reads b32 stride-1 (2 lanes/bank = free, m136); rows are
// wave-uniform broadcasts. Result pnew[] NOT stored (speculation support).
// err meaningful on lane 0 only.
template <bool TRACK>
__device__ __forceinline__ float half_compute(
    const float* __restrict__ cx, const float* __restrict__ cy,
    const float* __restrict__ cz, const float* __restrict__ cw,
    const float* __restrict__ rx, const float* __restrict__ ry,
    const float* __restrict__ rz, const float* __restrict__ rw,
    const float* __restrict__ pin, const float* __restrict__ pout_old,
    float (&pnew)[RPW], int i0, int lane, bool pin_zero, bool first_out) {
  float p2[KPL];
#pragma unroll
  for (int k = 0; k < KPL; ++k)
    p2[k] = pin_zero ? 0.f : gload(&pin[lane + (k << 6)]) * K2;

  float a0[RPW], a1[RPW], a2[RPW], X[RPW], m[RPW];
  float vals[RPW][KPL];
#pragma unroll
  for (int rr = 0; rr < RPW; ++rr) {
    a0[rr] = A2K * rx[i0 + rr]; a1[rr] = A2K * ry[i0 + rr];
    a2[rr] = A2K * rz[i0 + rr];
    X[rr] = -rw[i0 + rr];                 // rw = -K2*|r|^2
    m[rr] = -3.4e38f;
  }
#pragma unroll
  for (int k = 0; k < KPL; ++k) {
    const int j = lane + (k << 6);
    float ccx = cx[j], ccy = cy[j], ccz = cz[j];
    float base = cw[j] + p2[k];           // fold pin into the fma chain
#pragma unroll
    for (int rr = 0; rr < RPW; ++rr) {
      float t = fmaf(a0[rr], ccx, fmaf(a1[rr], ccy, fmaf(a2[rr], ccz, base)));
      float val = fminf(t - X[rr], p2[k]);  // = p2 - K2*max(C,0)
      vals[rr][k] = val;
      m[rr] = fmaxf(m[rr], val);
    }
  }
  float err = 0.f;
#pragma unroll
  for (int rr = 0; rr < RPW; ++rr) {
    float mr = wmax(m[rr]);
    float s = 0.f;
#pragma unroll
    for (int k = 0; k < KPL; ++k)
      s += __builtin_amdgcn_exp2f(vals[rr][k] - mr);
    s = wsum(s);
    float pn = fmaf(NEPSLN2, mr + __builtin_amdgcn_logf(s), EPSLOGMU);
    pnew[rr] = pn;
    if (TRACK && lane == 0) {
      float old = first_out ? 0.f : gload(&pout_old[i0 + rr]);
      err += fabsf(pn - old);
    }
  }
  return err;
}

__device__ __forceinline__ void store_rows(float* p, const float (&pnew)[RPW],
                                           int i0, int lane) {
  if (lane == 0) {
#pragma unroll
    for (int rr = 0; rr < RPW; ++rr) gstore(&p[i0 + rr], pnew[rr]);
  }
}

__global__ void __launch_bounds__(NTHREADS, 2) sinkhorn_kernel(
    const float* __restrict__ xg, const float* __restrict__ yg,
    float* __restrict__ out, float* __restrict__ ws) {
  __shared__ float s_xx[N], s_xy[N], s_xz[N], s_xw[N];  // w = -K2*|p|^2
  __shared__ float s_yx[N], s_yy[N], s_yz[N], s_yw[N];
  __shared__ float sh_red[NWAVES];

  const int bid = blockIdx.x;
  const int tid = threadIdx.x;
  const int b = bid & 7;
  const int seg = bid >> 3;
  const int wave = tid >> 6;
  const int lane = tid & 63;
  const int i0 = seg * SEG + wave * RPW;   // first of this wave's rows

  float* u = ws + OFF_U + b * N;
  float* v = ws + OFF_V + b * N;
  u64_t* flgA = (u64_t*)(ws + OFF_FLGA) + b * 32;  // arrival A + err payload
  u64_t* flgB = (u64_t*)(ws + OFF_FLGB) + b * 32;  // arrival B (+ emd payload)
  u64_t* errB = (u64_t*)(ws + OFF_ERRB);           // [4][8] ring
  u64_t* emdB = (u64_t*)(ws + OFF_EMD);            // [8]
  uint_t* init_flag = (uint_t*)(ws + OFF_INIT);

  // Block 0 zeroes the flag region FIRST (ws poisoned 0xAA: poison tag
  // 0xAAAAAAAA would falsely satisfy ">= epoch" polls), then MAGIC.
  if (bid == 0) {
    u64_t* zb = (u64_t*)(ws + OFF_ZERO);
    for (int i = tid; i < (OFF_ZEROEND - OFF_ZERO) / 2; i += NTHREADS)
      s64(&zb[i], 0ull);
    drain();
    __syncthreads();
    if (tid == 0) s32(init_flag, MAGIC);
  }

  // Stage points into LDS (SoA).
  for (int p = tid; p < N; p += NTHREADS) {
    const float* xp = xg + (size_t)(b * N + p) * 3;
    float x0 = xp[0], x1 = xp[1], x2 = xp[2];
    s_xx[p] = x0; s_xy[p] = x1; s_xz[p] = x2;
    s_xw[p] = -K2 * (x0 * x0 + x1 * x1 + x2 * x2);
    const float* yp = yg + (size_t)(b * N + p) * 3;
    float y0 = yp[0], y1 = yp[1], y2 = yp[2];
    s_yx[p] = y0; s_yy[p] = y1; s_yz[p] = y2;
    s_yw[p] = -K2 * (y0 * y0 + y1 * y1 + y2 * y2);
  }
  __syncthreads();

  // ---- u-half(0): u1 from v0=0 (no flags touched yet — MAGIC wait hidden) ----
  float un[RPW];
  float my_err = half_compute<true>(s_yx, s_yy, s_yz, s_yw,
                                    s_xx, s_xy, s_xz, s_xw,
                                    v, u, un, i0, lane,
                                    /*pin_zero=*/true, /*first_out=*/true);
  store_rows(u, un, i0, lane);
  drain();                                  // own u-stores acked
  float blk_err = block_sum(my_err, sh_red);
  if (tid == 0 && bid != 0)
    while (l32(init_flag) != MAGIC) __builtin_amdgcn_s_sleep(2);
  __syncthreads();
  // Arrival A carries the err payload — the arrival IS the publication.
  if (tid == 0) s64(&flgA[seg], pk64(1u, blk_err));

  int it = 0;
  for (;;) {
    const uint_t want = (uint_t)(it + 1);

    // ---- wait A: u_{it+1} visible; payloads = per-block errs(it) ----
    if (wave == 0) {
      float pay;
      for (;;) {
        u64_t pk = (lane < BPB) ? l64(&flgA[lane]) : ~0ull;
        if (__all((uint_t)(pk >> 32) >= want)) { pay = __uint_as_float((uint_t)pk); break; }
        __builtin_amdgcn_s_sleep(1);
      }
      // seg0 publishes batch err IMMEDIATELY (propagates during v-half +
      // bar B + spec-u before the decision consumes it).
      if (seg == 0) {
        float e = wsum((lane < BPB) ? pay : 0.f);
        if (lane == 0) s64(&errB[(it & 3) * 8 + b], pk64(want, e));
      }
    }
    __syncthreads();

    // ---- v-half(it): v_{it+1} from u_{it+1} ----
    float vn[RPW];
    half_compute<false>(s_xx, s_xy, s_xz, s_xw,
                        s_yx, s_yy, s_yz, s_yw,
                        u, nullptr, vn, i0, lane, false, false);
    store_rows(v, vn, i0, lane);
    drain();
    __syncthreads();
    if (tid == 0) s64(&flgB[seg], pk64(want, 0.f));

    // ---- wait B: v_{it+1} visible ----
    if (wave == 0) {
      for (;;) {
        u64_t pk = (lane < BPB) ? l64(&flgB[lane]) : ~0ull;
        if (__all((uint_t)(pk >> 32) >= want)) break;
        __builtin_amdgcn_s_sleep(1);
      }
    }
    __syncthreads();

    if (it == MAX_ITER - 1) break;          // reference caps at 100 steps

    // ---- speculative u-half(it+1): u_{it+2} in regs, store deferred ----
    my_err = half_compute<true>(s_yx, s_yy, s_yz, s_yw,
                                s_xx, s_xy, s_xz, s_xw,
                                v, u, un, i0, lane, false, false);

    // ---- decision(it): errB flags published ~one half-update ago ----
    if (wave == 0) {
      float pay;
      for (;;) {
        u64_t pk = (lane < B) ? l64(&errB[(it & 3) * 8 + lane]) : ~0ull;
        if (__all((uint_t)(pk >> 32) >= want)) { pay = __uint_as_float((uint_t)pk); break; }
        __builtin_amdgcn_s_sleep(1);
      }
      float e = wsum((lane < B) ? pay : 0.f);
      if (lane == 0) sh_red[0] = e;
    }
    __syncthreads();
    float tot = sh_red[0];
    __syncthreads();
    if (tot * (1.f / (B * N)) < THRESH) break;  // keep u_{it+1}, v_{it+1}

    // ---- commit speculation (all err(it) consumers are past — gated by
    // the decision we just passed) ----
    store_rows(u, un, i0, lane);
    drain();
    blk_err = block_sum(my_err, sh_red);
    if (tid == 0) s64(&flgA[seg], pk64((uint_t)(it + 2), blk_err));
    ++it;
  }

  // ---- epilogue: emd_b = sum_ij exp((u_i+v_j-C)/EPS)*C  (in K2 scale) ----
  float p2e[KPL];
#pragma unroll
  for (int k = 0; k < KPL; ++k) p2e[k] = gload(&v[lane + (k << 6)]) * K2;
  float acc = 0.f;
#pragma unroll
  for (int rr = 0; rr < RPW; ++rr) {
    const int i = i0 + rr;
    float a0 = A2K * s_xx[i], a1 = A2K * s_xy[i], a2 = A2K * s_xz[i];
    float X = -s_xw[i];
    float u2 = gload(&u[i]) * K2;
#pragma unroll
    for (int k = 0; k < KPL; ++k) {
      const int j = lane + (k << 6);
      float t = fmaf(a0, s_yx[j], fmaf(a1, s_yy[j], fmaf(a2, s_yz[j], s_yw[j])));
      float kc = fmaxf(X - t, 0.f);   // K2*C
      acc = fmaf(__builtin_amdgcn_exp2f(u2 + p2e[k] - kc), kc, acc);
    }
  }
  float blk = block_sum(acc, sh_red);
  const uint_t ef = (uint_t)(it + 2);   // it is grid-uniform at exit
  // Arrival B reused, payload = block emd partial. No drain needed: the
  // payload travels IN the flag word.
  if (tid == 0) s64(&flgB[seg], pk64(ef, blk));

  // Fused reduction: non-seg0 blocks exit now; seg0 combines its batch;
  // block 0 combines batches.
  if (seg == 0 && wave == 0) {
    float pay;
    for (;;) {
      u64_t pk = (lane < BPB) ? l64(&flgB[lane]) : ~0ull;
      if (__all((uint_t)(pk >> 32) >= ef)) { pay = __uint_as_float((uint_t)pk); break; }
      __builtin_amdgcn_s_sleep(1);
    }
    float e = wsum((lane < BPB) ? pay : 0.f);
    if (lane == 0) s64(&emdB[b], pk64(1u, e));
  }
  if (bid == 0 && wave == 0) {
    float pay;
    for (;;) {
      u64_t pk = (lane < B) ? l64(&emdB[lane]) : ~0ull;
      if (__all((uint_t)(pk >> 32) >= 1u)) { pay = __uint_as_float((uint_t)pk); break; }
      __builtin_amdgcn_s_sleep(1);
    }
    float e = wsum((lane < B) ? pay : 0.f);
    if (lane == 0) out[0] = e * (1.f / (B * K2));
  }
}

extern "C" void kernel_launch(void* const* d_in, const int* in_sizes, int n_in,
                              void* d_out, int out_size, void* d_ws, size_t ws_size,
                              hipStream_t stream) {
  const float* x = (const float*)d_in[0];
  const float* y = (const float*)d_in[1];
  float* out = (float*)d_out;
  float* ws = (float*)d_ws;
  void* args[] = { (void*)&x, (void*)&y, (void*)&out, (void*)&ws };
  // Cooperative launch only for the co-residency guarantee (no cg::grid.sync;
  // all sync is payload-carrying epoch flags over coherent atomics).
  hipLaunchCooperativeKernel((const void*)sinkhorn_kernel,
                             dim3(NBLOCKS), dim3(NTHREADS), args, 0, stream);
}

// Round 9
// 107.537 us; speedup vs baseline: 1.2879x; 1.0259x over previous
//
#include <hip/hip_runtime.h>

typedef unsigned int uint_t;
typedef unsigned long long u64_t;

constexpr int B = 8;
constexpr int N = 1024;
constexpr int NBLOCKS = 256;
constexpr int NTHREADS = 512;              // proven regime: ~84-100 VGPR, no spill
constexpr int NWAVES = NTHREADS / 64;      // 8
constexpr int BPB = NBLOCKS / B;           // 32 blocks per batch
constexpr int SEG = N / BPB;               // 32 rows per block
constexpr int RPW = SEG / NWAVES;          // 4 rows per wave
constexpr int KPL = N / 64;                // 16 columns per lane
constexpr int MAX_ITER = 100;
constexpr float THRESH = 0.1f;
constexpr float K2 = 14.42695040888963f;         // log2(e)/EPS
constexpr float A2K = 2.0f * K2;
constexpr float NEPSLN2 = -0.06931471805599453f; // -EPS*ln2
constexpr float EPSLOGMU = -0.693146156565634f;  // EPS*log(1/N+1e-8)
constexpr uint_t MAGIC = 0xC0FFEE01u;

// ws word offsets (flag offsets even -> 8B aligned)
constexpr int OFF_U    = 0;                 // [B][N] floats (single buffer: all
constexpr int OFF_V    = OFF_U + B * N;     // [B][N]  readers proven done before overwrite)
constexpr int OFF_ZERO = OFF_V + B * N;     // ---- zeroed region (u64 flags) ----
constexpr int OFF_FLGA = OFF_ZERO;          // [8][32] u64: (epoch<<32)|blk_err
constexpr int OFF_FLGB = OFF_FLGA + 512;    // [8][32] u64: (epoch<<32)|payload (emd at end)
constexpr int OFF_ERRB = OFF_FLGB + 512;    // [4][8] u64 ring: (it+1<<32)|batch_err
constexpr int OFF_ZEROEND = OFF_ERRB + 64;
constexpr int OFF_INIT = OFF_ZEROEND;       // [1] uint (MAGIC; poison != MAGIC)

// ---- coherent (sc1) access helpers: bypass non-coherent L1/L2 ----
__device__ __forceinline__ float gload(const float* p) {
  return __hip_atomic_load(p, __ATOMIC_RELAXED, __HIP_MEMORY_SCOPE_AGENT);
}
__device__ __forceinline__ void gstore(float* p, float v) {
  __hip_atomic_store(p, v, __ATOMIC_RELAXED, __HIP_MEMORY_SCOPE_AGENT);
}
__device__ __forceinline__ uint_t l32(const uint_t* p) {
  return __hip_atomic_load(p, __ATOMIC_RELAXED, __HIP_MEMORY_SCOPE_AGENT);
}
__device__ __forceinline__ void s32(uint_t* p, uint_t v) {
  __hip_atomic_store(p, v, __ATOMIC_RELAXED, __HIP_MEMORY_SCOPE_AGENT);
}
__device__ __forceinline__ u64_t l64(const u64_t* p) {
  return __hip_atomic_load(p, __ATOMIC_RELAXED, __HIP_MEMORY_SCOPE_AGENT);
}
__device__ __forceinline__ void s64(u64_t* p, u64_t v) {
  __hip_atomic_store(p, v, __ATOMIC_RELAXED, __HIP_MEMORY_SCOPE_AGENT);
}
// Per-wave drain: own stores acked at the coherence point before we flag.
__device__ __forceinline__ void drain() { __builtin_amdgcn_s_waitcnt(0); }

__device__ __forceinline__ u64_t pk64(uint_t tag, float v) {
  return ((u64_t)tag << 32) | (u64_t)__float_as_uint(v);
}

__device__ __forceinline__ float wsum(float v) {
#pragma unroll
  for (int o = 32; o; o >>= 1) v += __shfl_xor(v, o);
  return v;
}
__device__ __forceinline__ float wmax(float v) {
#pragma unroll
  for (int o = 32; o; o >>= 1) v = fmaxf(v, __shfl_xor(v, o));
  return v;
}

// Deterministic block-wide sum; every thread returns the same value.
__device__ __forceinline__ float block_sum(float v, float* sh) {
  v = wsum(v);
  const int wave = threadIdx.x >> 6;
  const int lane = threadIdx.x & 63;
  if (lane == 0) sh[wave] = v;
  __syncthreads();
  float tot = 0.f;
#pragma unroll
  for (int w = 0; w < NWAVES; ++w) tot += sh[w];
  __syncthreads();
  return tot;
}

// One Sinkhorn half-update in base-2 scale. Cols from float2-pair LDS
// (2x ds_read_b64, stride-1 in float2 units = conflict-free); rows are
// wave-uniform broadcasts. Rows are STORED IMMEDIATELY as computed (store-ack
// latency overlaps the remaining reduction). prev[] supplies the old value
// for err tracking (registers, no gload). err meaningful on lane 0 only.
template <bool TRACK, bool PIN_ZERO>
__device__ __forceinline__ float half_compute(
    const float2* __restrict__ cxy, const float2* __restrict__ czw,
    const float2* __restrict__ rxy, const float2* __restrict__ rzw,
    const float* __restrict__ pin, float* __restrict__ pout,
    const float (&prev)[RPW], float (&pnew)[RPW], int i0, int lane) {
  float p2[KPL];
#pragma unroll
  for (int k = 0; k < KPL; ++k)
    p2[k] = PIN_ZERO ? 0.f : gload(&pin[lane + (k << 6)]) * K2;

  float a0[RPW], a1[RPW], a2[RPW], X[RPW], m[RPW];
  float vals[RPW][KPL];
#pragma unroll
  for (int rr = 0; rr < RPW; ++rr) {
    float2 rA = rxy[i0 + rr], rB = rzw[i0 + rr];   // broadcast
    a0[rr] = A2K * rA.x; a1[rr] = A2K * rA.y; a2[rr] = A2K * rB.x;
    X[rr] = -rB.y;                       // rB.y = -K2*|r|^2
    m[rr] = -3.4e38f;
  }
#pragma unroll
  for (int k = 0; k < KPL; ++k) {
    const int j = lane + (k << 6);
    float2 cA = cxy[j], cB = czw[j];
    float base = cB.y + p2[k];           // fold pin into the fma chain
#pragma unroll
    for (int rr = 0; rr < RPW; ++rr) {
      float t = fmaf(a0[rr], cA.x, fmaf(a1[rr], cA.y, fmaf(a2[rr], cB.x, base)));
      float val = fminf(t - X[rr], p2[k]);  // = p2 - K2*max(C,0)
      vals[rr][k] = val;
      m[rr] = fmaxf(m[rr], val);
    }
  }
  float err = 0.f;
#pragma unroll
  for (int rr = 0; rr < RPW; ++rr) {
    float mr = wmax(m[rr]);
    float s = 0.f;
#pragma unroll
    for (int k = 0; k < KPL; ++k)
      s += __builtin_amdgcn_exp2f(vals[rr][k] - mr);
    s = wsum(s);
    float pn = fmaf(NEPSLN2, mr + __builtin_amdgcn_logf(s), EPSLOGMU);
    pnew[rr] = pn;
    if (lane == 0) {
      gstore(&pout[i0 + rr], pn);        // immediate: ack overlaps next rows
      if (TRACK) err += fabsf(pn - prev[rr]);
    }
  }
  return err;
}

__global__ void __launch_bounds__(NTHREADS, 2) sinkhorn_kernel(
    const float* __restrict__ xg, const float* __restrict__ yg,
    float* __restrict__ out, float* __restrict__ ws) {
  __shared__ float2 s_xxy[N], s_xzw[N];   // (x,y) and (z, -K2*|p|^2)
  __shared__ float2 s_yxy[N], s_yzw[N];
  __shared__ float sh_red[NWAVES];

  const int bid = blockIdx.x;
  const int tid = threadIdx.x;
  const int b = bid & 7;
  const int seg = bid >> 3;
  const int wave = tid >> 6;
  const int lane = tid & 63;
  const int i0 = seg * SEG + wave * RPW;   // first of this wave's rows

  float* u = ws + OFF_U + b * N;
  float* v = ws + OFF_V + b * N;
  u64_t* flgA = (u64_t*)(ws + OFF_FLGA) + b * 32;
  u64_t* flgB = (u64_t*)(ws + OFF_FLGB) + b * 32;
  u64_t* flgB_all = (u64_t*)(ws + OFF_FLGB);       // [256] for epilogue
  u64_t* errB = (u64_t*)(ws + OFF_ERRB);           // [4][8] ring
  uint_t* init_flag = (uint_t*)(ws + OFF_INIT);

  // Block 0 zeroes the flag region FIRST (ws poisoned 0xAA would satisfy
  // ">= epoch" polls), then broadcasts MAGIC.
  if (bid == 0) {
    u64_t* zb = (u64_t*)(ws + OFF_ZERO);
    for (int i = tid; i < (OFF_ZEROEND - OFF_ZERO) / 2; i += NTHREADS)
      s64(&zb[i], 0ull);
    drain();
    __syncthreads();
    if (tid == 0) s32(init_flag, MAGIC);
  }

  // Stage points into LDS: fully-coalesced (3x float2 contiguous per thread
  // covers 2 points), then repack. 512 threads x 6 floats = 3072 = N*3.
  {
    const float2* xp = (const float2*)(xg + (size_t)b * N * 3) + 3 * tid;
    float2 g0 = xp[0], g1 = xp[1], g2 = xp[2];
    s_xxy[2 * tid]     = g0;
    s_xzw[2 * tid]     = make_float2(g1.x, -K2 * (g0.x * g0.x + g0.y * g0.y + g1.x * g1.x));
    s_xxy[2 * tid + 1] = make_float2(g1.y, g2.x);
    s_xzw[2 * tid + 1] = make_float2(g2.y, -K2 * (g1.y * g1.y + g2.x * g2.x + g2.y * g2.y));
    const float2* yp = (const float2*)(yg + (size_t)b * N * 3) + 3 * tid;
    float2 h0 = yp[0], h1 = yp[1], h2 = yp[2];
    s_yxy[2 * tid]     = h0;
    s_yzw[2 * tid]     = make_float2(h1.x, -K2 * (h0.x * h0.x + h0.y * h0.y + h1.x * h1.x));
    s_yxy[2 * tid + 1] = make_float2(h1.y, h2.x);
    s_yzw[2 * tid + 1] = make_float2(h2.y, -K2 * (h1.y * h1.y + h2.x * h2.x + h2.y * h2.y));
  }
  __syncthreads();

  // ---- u-half(0): u1 from v0=0; stores immediate; MAGIC wait hidden ----
  float un[RPW], un_prev[RPW];
#pragma unroll
  for (int rr = 0; rr < RPW; ++rr) un_prev[rr] = 0.f;
  float my_err = half_compute<true, true>(s_yxy, s_yzw, s_xxy, s_xzw,
                                          v, u, un_prev, un, i0, lane);
  drain();                                  // own u-stores acked
  float werr = wsum(my_err);                // lane0 partial -> all lanes
  if (lane == 0) sh_red[wave] = werr;
  if (tid == 0 && bid != 0)
    while (l32(init_flag) != MAGIC) __builtin_amdgcn_s_sleep(2);
  __syncthreads();
  if (tid == 0) {
    float e = 0.f;
#pragma unroll
    for (int w = 0; w < NWAVES; ++w) e += sh_red[w];
    s64(&flgA[seg], pk64(1u, e));          // arrival IS the err publication
  }

  int it = 0;
  int final_it;                             // = converged iteration count
  bool use_prev;                            // epilogue u from un_prev or un
  for (;;) {
    const uint_t want = (uint_t)(it + 1);

    // ---- wait A: u_{it+1} visible; payloads = per-block errs(it) ----
    if (wave == 0) {
      float pay;
      for (;;) {
        u64_t pk = (lane < BPB) ? l64(&flgA[lane]) : ~0ull;
        if (__all((uint_t)(pk >> 32) >= want)) { pay = __uint_as_float((uint_t)pk); break; }
        __builtin_amdgcn_s_sleep(1);
      }
      if (seg == 0) {                       // publish batch err(it) now
        float e = wsum((lane < BPB) ? pay : 0.f);
        if (lane == 0) s64(&errB[(it & 3) * 8 + b], pk64(want, e));
      }
    }
    __syncthreads();

    // ---- v-half(it): v_{it+1} from u_{it+1}; stores immediate ----
    float vn[RPW], vdummy[RPW];
    half_compute<false, false>(s_xxy, s_xzw, s_yxy, s_yzw,
                               u, v, vdummy, vn, i0, lane);
    drain();
    __syncthreads();
    if (tid == 0) s64(&flgB[seg], pk64(want, 0.f));

    // ---- wait B: v_{it+1} visible ----
    if (wave == 0) {
      for (;;) {
        u64_t pk = (lane < BPB) ? l64(&flgB[lane]) : ~0ull;
        if (__all((uint_t)(pk >> 32) >= want)) break;
        __builtin_amdgcn_s_sleep(1);
      }
    }
    __syncthreads();

    if (it == MAX_ITER - 1) { final_it = it + 1; use_prev = false; break; }

    // Prefetch decision(it) inputs NOW (published at wait A, ~2 halves ago;
    // consumed after the u-half below -> latency fully hidden).
    u64_t dpre = (lane < B) ? l64(&errB[(it & 3) * 8 + lane]) : ~0ull;

    // ---- u-half(it+1): u_{it+2} committed unconditionally (safe: all
    // v-half readers of u_{it+1} finished before their flagB; epilogue's
    // own-row u comes from registers) ----
#pragma unroll
    for (int rr = 0; rr < RPW; ++rr) un_prev[rr] = un[rr];
    my_err = half_compute<true, false>(s_yxy, s_yzw, s_xxy, s_xzw,
                                       v, u, un_prev, un, i0, lane);
    drain();
    werr = wsum(my_err);
    if (lane == 0) sh_red[wave] = werr;
    __syncthreads();
    if (tid == 0) {
      float e = 0.f;
#pragma unroll
      for (int w = 0; w < NWAVES; ++w) e += sh_red[w];
      s64(&flgA[seg], pk64((uint_t)(it + 2), e));
    }

    // ---- lagged decision(it): per-wave, prefetched (same verdict in every
    // wave once visible -> uniform break) ----
    float tot;
    for (;;) {
      if (__all((uint_t)(dpre >> 32) >= want)) {
        tot = wsum((lane < B) ? __uint_as_float((uint_t)dpre) : 0.f);
        break;
      }
      __builtin_amdgcn_s_sleep(1);
      dpre = (lane < B) ? l64(&errB[(it & 3) * 8 + lane]) : ~0ull;
    }
    if (tot * (1.f / (B * N)) < THRESH) {
      final_it = it + 1; use_prev = true;   // keep u_{it+1} (= un_prev), v_{it+1}
      break;
    }
    ++it;
  }

  // ---- epilogue: emd_b = sum_ij exp((u_i+v_j-C)/EPS)*C  (in K2 scale).
  // v in memory is v_{final} (never overwritten after break); own-row u
  // comes from registers.
  float p2e[KPL];
#pragma unroll
  for (int k = 0; k < KPL; ++k) p2e[k] = gload(&v[lane + (k << 6)]) * K2;
  float acc = 0.f;
#pragma unroll
  for (int rr = 0; rr < RPW; ++rr) {
    const int i = i0 + rr;
    float2 rA = s_xxy[i], rB = s_xzw[i];
    float a0 = A2K * rA.x, a1 = A2K * rA.y, a2 = A2K * rB.x;
    float X = -rB.y;
    float u2 = (use_prev ? un_prev[rr] : un[rr]) * K2;
#pragma unroll
    for (int k = 0; k < KPL; ++k) {
      const int j = lane + (k << 6);
      float2 cA = s_yxy[j], cB = s_yzw[j];
      float t = fmaf(a0, cA.x, fmaf(a1, cA.y, fmaf(a2, cB.x, cB.y)));
      float kc = fmaxf(X - t, 0.f);   // K2*C
      acc = fmaf(__builtin_amdgcn_exp2f(u2 + p2e[k] - kc), kc, acc);
    }
  }
  float blk = block_sum(acc, sh_red);
  const uint_t ef = (uint_t)(final_it + 1);  // distinct from all barrier epochs
  if (tid == 0) s64(&flgB[seg], pk64(ef, blk));

  // Single-level fused reduction: block 0 polls ALL 256 payload flags
  // (waves 0-3, 64 each) -> one IC hop instead of two.
  if (bid == 0) {
    float part = 0.f;
    if (wave < 4) {
      u64_t pk;
      for (;;) {
        pk = l64(&flgB_all[(wave << 6) + lane]);
        if (__all((uint_t)(pk >> 32) >= ef)) break;
        __builtin_amdgcn_s_sleep(1);
      }
      part = __uint_as_float((uint_t)pk);
    }
    float tot = block_sum(part, sh_red);
    if (tid == 0) out[0] = tot * (1.f / (B * K2));
  }
}

extern "C" void kernel_launch(void* const* d_in, const int* in_sizes, int n_in,
                              void* d_out, int out_size, void* d_ws, size_t ws_size,
                              hipStream_t stream) {
  const float* x = (const float*)d_in[0];
  const float* y = (const float*)d_in[1];
  float* out = (float*)d_out;
  float* ws = (float*)d_ws;
  void* args[] = { (void*)&x, (void*)&y, (void*)&out, (void*)&ws };
  // Cooperative launch only for the co-residency guarantee (no cg::grid.sync;
  // all sync is payload-carrying epoch flags over coherent atomics).
  hipLaunchCooperativeKernel((const void*)sinkhorn_kernel,
                             dim3(NBLOCKS), dim3(NTHREADS), args, 0, stream);
}